// Round 1
// baseline (2540.326 us; speedup 1.0000x reference)
//
#include <hip/hip_runtime.h>
#include <hip/hip_bf16.h>

typedef __hip_bfloat16 bf16;
typedef __attribute__((ext_vector_type(8))) short short8;
typedef __attribute__((ext_vector_type(4))) float f32x4;

typedef __attribute__((address_space(1))) void gvoid;
typedef __attribute__((address_space(3))) void lvoid;

__device__ __forceinline__ void async16(const void* g, void* l) {
  __builtin_amdgcn_global_load_lds((gvoid*)g, (lvoid*)l, 16, 0, 0);
}

#define BM 128
#define BN 128
#define BKT 64

// NT GEMM: C[M,N] = A[M,K] (row-major) * B[N,K]^T (row-major), bf16 in, fp32 acc.
// EPI: 0 = none, 1 = relu(x + bias[col]), 3 = aux*(x + bias[col]) + prevF (DCN cross)
template<int EPI>
__global__ void __launch_bounds__(256)
gemm_bt(const bf16* __restrict__ A, const bf16* __restrict__ B,
        int M, int N, int K,
        const float* __restrict__ bias, const float* __restrict__ aux,
        const float* prevF, float* outF, int ldF,
        bf16* __restrict__ outB, int ldB)
{
  __shared__ __align__(16) bf16 As[BM * BKT];
  __shared__ __align__(16) bf16 Bs[BN * BKT];

  const int tid  = threadIdx.x;
  const int lane = tid & 63;
  const int wid  = tid >> 6;
  const int wm   = (wid >> 1) * 64;   // wave row offset within 128-tile
  const int wn   = (wid & 1) * 64;    // wave col offset
  const long tileM = (long)blockIdx.y * BM;
  const long tileN = (long)blockIdx.x * BN;

  // Staging: 1024 16B-units per tile; unit u holds row=u>>3, kgroup g=(u&7)^(row&7) (XOR swizzle).
  const bf16* aP[4]; const bf16* bP[4]; bf16* lA[4]; bf16* lB[4];
#pragma unroll
  for (int i = 0; i < 4; ++i) {
    int u = i * 256 + tid;
    int row = u >> 3;
    int g = (u & 7) ^ (row & 7);
    aP[i] = A + (tileM + row) * (long)K + g * 8;
    bP[i] = B + (tileN + row) * (long)K + g * 8;
    lA[i] = As + u * 8;
    lB[i] = Bs + u * 8;
  }

  f32x4 acc[4][4] = {};

  for (int k0 = 0; k0 < K; k0 += BKT) {
#pragma unroll
    for (int i = 0; i < 4; ++i) {
      async16(aP[i], lA[i]);
      async16(bP[i], lB[i]);
      aP[i] += BKT; bP[i] += BKT;
    }
    __syncthreads();   // drains vmcnt for global_load_lds
#pragma unroll
    for (int ks = 0; ks < 2; ++ks) {
      short8 af[4], bfr[4];
      const int g = ks * 4 + (lane >> 4);
#pragma unroll
      for (int t = 0; t < 4; ++t) {
        int ra = wm + t * 16 + (lane & 15);
        af[t]  = *(const short8*)(As + (ra * 8 + (g ^ (ra & 7))) * 8);
        int rb = wn + t * 16 + (lane & 15);
        bfr[t] = *(const short8*)(Bs + (rb * 8 + (g ^ (rb & 7))) * 8);
      }
#pragma unroll
      for (int ti = 0; ti < 4; ++ti)
#pragma unroll
        for (int tj = 0; tj < 4; ++tj)
          acc[ti][tj] = __builtin_amdgcn_mfma_f32_16x16x32_bf16(af[ti], bfr[tj], acc[ti][tj], 0, 0, 0);
    }
    __syncthreads();
  }

  // Epilogue. C/D layout: col = lane&15, row = (lane>>4)*4 + reg  [measured m89/m91]
  const int cn = lane & 15;
  const int r0 = (lane >> 4) * 4;
#pragma unroll
  for (int ti = 0; ti < 4; ++ti) {
#pragma unroll
    for (int tj = 0; tj < 4; ++tj) {
      long gc = tileN + wn + tj * 16 + cn;
#pragma unroll
      for (int r = 0; r < 4; ++r) {
        long gr = tileM + wm + ti * 16 + r0 + r;
        float v = acc[ti][tj][r];
        if (EPI == 1) v = fmaxf(v + bias[gc], 0.f);
        if (EPI == 3) {
          v += bias[gc];
          long o = gr * (long)N + gc;
          v = aux[o] * v + prevF[o];
        }
        if (outF) outF[gr * (long)ldF + gc] = v;
        if (outB) outB[gr * (long)ldB + gc] = __float2bfloat16(v);
      }
    }
  }
}

// Multi-table embedding-bag sum. One wave per (table,bag). Bag ranges per
// searchsorted(off, ., 'right')-1 clipped to [0,B-1]:
//   bag 0 -> [0, off[1]), bag b -> [off[b], off[b+1]), bag B-1 -> [off[B-1], nt)
__global__ void __launch_bounds__(256)
emb_pool(const float* __restrict__ tables, const int* __restrict__ indices,
         const int* __restrict__ offsets, float* __restrict__ combF,
         bf16* __restrict__ combB)
{
  const int bag  = blockIdx.x * 4 + (threadIdx.x >> 6);
  const int lane = threadIdx.x & 63;
  const int t = bag >> 12;        // / 4096
  const int b = bag & 4095;
  const int nt = 81920;           // B * L
  int lo = (b == 0)    ? 0  : offsets[t * 4096 + b];
  int hi = (b == 4095) ? nt : offsets[t * 4096 + b + 1];
  const int*   idx = indices + (long)t * nt;
  const float* tab = tables + (long)t * 100000 * 128;
  float ax = 0.f, ay = 0.f;
  for (int j = lo; j < hi; ++j) {
    const float2* src = (const float2*)(tab + (long)idx[j] * 128);
    float2 v = src[lane];
    ax += v.x; ay += v.y;
  }
  long o = ((long)b * 27 + 1 + t) * 128 + lane * 2;
  *(float2*)(combF + o) = make_float2(ax, ay);
  combB[o]     = __float2bfloat16(ax);
  combB[o + 1] = __float2bfloat16(ay);
}

// Bottom MLP layer 0: [4096,13] @ W0[512,13]^T + b0, ReLU, bf16 out.
__global__ void __launch_bounds__(256)
bot0_kern(const float* __restrict__ x, const float* __restrict__ W,
          const float* __restrict__ bias, bf16* __restrict__ out)
{
  int i = blockIdx.x * 256 + threadIdx.x;   // 4096*512 threads
  int col = i & 511, row = i >> 9;
  const float* xr = x + (long)row * 13;
  const float* wr = W + (long)col * 13;
  float acc = bias[col];
#pragma unroll
  for (int k = 0; k < 13; ++k) acc += xr[k] * wr[k];
  out[i] = __float2bfloat16(fmaxf(acc, 0.f));
}

// Top MLP last layer: z2[4096,512] @ W3[1,512]^T + b3 -> out[4096]
__global__ void __launch_bounds__(256)
top3_kern(const float* __restrict__ z2, const float* __restrict__ W3,
          const float* __restrict__ b3, float* __restrict__ out)
{
  int row  = blockIdx.x * 4 + (threadIdx.x >> 6);
  int lane = threadIdx.x & 63;
  const float* zr = z2 + (long)row * 512;
  float acc = 0.f;
#pragma unroll
  for (int k = 0; k < 8; ++k) {
    int c = lane + 64 * k;
    acc += zr[c] * W3[c];
  }
#pragma unroll
  for (int off = 32; off > 0; off >>= 1) acc += __shfl_down(acc, off, 64);
  if (lane == 0) out[row] = acc + b3[0];
}

__global__ void f2b_kern(const float* __restrict__ in, bf16* __restrict__ out, int n)
{
  int i = blockIdx.x * 256 + threadIdx.x;
  if (i < n) out[i] = __float2bfloat16(in[i]);
}

extern "C" void kernel_launch(void* const* d_in, const int* in_sizes, int n_in,
                              void* d_out, int out_size, void* d_ws, size_t ws_size,
                              hipStream_t stream)
{
  const float* dense   = (const float*)d_in[0];
  const int*   indices = (const int*)d_in[1];
  const int*   offsets = (const int*)d_in[2];
  const float* tables  = (const float*)d_in[3];
  const float* botW0 = (const float*)d_in[4];
  const float* botb0 = (const float*)d_in[5];
  const float* botW1 = (const float*)d_in[6];
  const float* botb1 = (const float*)d_in[7];
  const float* botW2 = (const float*)d_in[8];
  const float* botb2 = (const float*)d_in[9];
  const float* dcnW  = (const float*)d_in[10];
  const float* dcnV  = (const float*)d_in[11];
  const float* dcnb  = (const float*)d_in[12];
  const float* topW0 = (const float*)d_in[13];
  const float* topb0 = (const float*)d_in[14];
  const float* topW1 = (const float*)d_in[15];
  const float* topb1 = (const float*)d_in[16];
  const float* topW2 = (const float*)d_in[17];
  const float* topb2 = (const float*)d_in[18];
  const float* topW3 = (const float*)d_in[19];
  const float* topb3 = (const float*)d_in[20];
  float* out = (float*)d_out;

  const int Bb = 4096, F = 3456;
  char* p = (char*)d_ws;
  auto alloc = [&](size_t bytes) -> void* {
    void* r = (void*)p; p += (bytes + 255) & ~(size_t)255; return r;
  };
  float* combF = (float*)alloc((size_t)Bb * F * 4);
  bf16*  combB = (bf16*) alloc((size_t)Bb * F * 2);
  float* xlF   = (float*)alloc((size_t)Bb * F * 4);
  bf16*  xlB   = (bf16*) alloc((size_t)Bb * F * 2);
  bf16*  xvB   = (bf16*) alloc((size_t)Bb * 512 * 2);
  bf16*  bot0B = (bf16*) alloc((size_t)Bb * 512 * 2);
  bf16*  bot1B = (bf16*) alloc((size_t)Bb * 256 * 2);
  bf16*  z0B   = (bf16*) alloc((size_t)Bb * 1024 * 2);
  bf16*  z1B   = (bf16*) alloc((size_t)Bb * 1024 * 2);
  float* z2F   = (float*)alloc((size_t)Bb * 512 * 4);
  bf16*  dcnVB = (bf16*) alloc((size_t)3 * 512 * F * 2);
  bf16*  dcnWB = (bf16*) alloc((size_t)3 * F * 512 * 2);
  bf16*  topW0B= (bf16*) alloc((size_t)1024 * F * 2);
  bf16*  topW1B= (bf16*) alloc((size_t)1024 * 1024 * 2);
  bf16*  topW2B= (bf16*) alloc((size_t)512 * 1024 * 2);
  bf16*  botW1B= (bf16*) alloc((size_t)256 * 512 * 2);
  bf16*  botW2B= (bf16*) alloc((size_t)128 * 256 * 2);

  auto cvt = [&](const float* s, bf16* d, int n) {
    f2b_kern<<<(n + 255) / 256, 256, 0, stream>>>(s, d, n);
  };
  cvt(botW1, botW1B, 256 * 512);
  cvt(botW2, botW2B, 128 * 256);
  cvt(dcnV,  dcnVB,  3 * 512 * F);
  cvt(dcnW,  dcnWB,  3 * F * 512);
  cvt(topW0, topW0B, 1024 * F);
  cvt(topW1, topW1B, 1024 * 1024);
  cvt(topW2, topW2B, 512 * 1024);

  bot0_kern<<<(Bb * 512) / 256, 256, 0, stream>>>(dense, botW0, botb0, bot0B);

  // bottom MLP L1: [4096,512] -> [4096,256]
  gemm_bt<1><<<dim3(256 / BN, Bb / BM), 256, 0, stream>>>(
      bot0B, botW1B, Bb, 256, 512, botb1, nullptr, nullptr, nullptr, 0, bot1B, 256);
  // bottom MLP L2: -> combined[:, 0:128]
  gemm_bt<1><<<dim3(1, Bb / BM), 256, 0, stream>>>(
      bot1B, botW2B, Bb, 128, 256, botb2, nullptr, nullptr, combF, F, combB, F);

  // embedding bags -> combined[:, 128:3456]
  emb_pool<<<(26 * Bb) / 4, 256, 0, stream>>>(tables, indices, offsets, combF, combB);

  // DCN cross layers
  for (int l = 0; l < 3; ++l) {
    const bf16*  xin  = (l == 0) ? combB : xlB;
    const float* prev = (l == 0) ? combF : xlF;
    gemm_bt<0><<<dim3(512 / BN, Bb / BM), 256, 0, stream>>>(
        xin, dcnVB + (size_t)l * 512 * F, Bb, 512, F,
        nullptr, nullptr, nullptr, nullptr, 0, xvB, 512);
    gemm_bt<3><<<dim3(F / BN, Bb / BM), 256, 0, stream>>>(
        xvB, dcnWB + (size_t)l * F * 512, Bb, F, 512,
        dcnb + (size_t)l * F, combF, prev, xlF, F, xlB, F);
  }

  // top MLP
  gemm_bt<1><<<dim3(1024 / BN, Bb / BM), 256, 0, stream>>>(
      xlB, topW0B, Bb, 1024, F, topb0, nullptr, nullptr, nullptr, 0, z0B, 1024);
  gemm_bt<1><<<dim3(1024 / BN, Bb / BM), 256, 0, stream>>>(
      z0B, topW1B, Bb, 1024, 1024, topb1, nullptr, nullptr, nullptr, 0, z1B, 1024);
  gemm_bt<1><<<dim3(512 / BN, Bb / BM), 256, 0, stream>>>(
      z1B, topW2B, Bb, 512, 1024, topb2, nullptr, nullptr, z2F, 512, nullptr, 0);
  top3_kern<<<Bb / 4, 256, 0, stream>>>(z2F, topW3, topb3, out);
}